// Round 1
// baseline (38246.594 us; speedup 1.0000x reference)
//
#include <hip/hip_runtime.h>
#include <math.h>

#define BB 2
#define SS 1024
#define HH 16
#define DD 1024
#define DHH 64
#define FFDIM 4096
#define VV 32000
#define LL 8
#define MM (BB * SS)

// ---------------- block reduce helpers (blockDim.x == 256 → 4 waves) --------
__device__ __forceinline__ float block_reduce_sum(float val, float* red) {
    int lane = threadIdx.x & 63, wv = threadIdx.x >> 6;
#pragma unroll
    for (int off = 32; off; off >>= 1) val += __shfl_down(val, off, 64);
    if (lane == 0) red[wv] = val;
    __syncthreads();
    float t = red[0] + red[1] + red[2] + red[3];
    __syncthreads();
    return t;
}

__device__ __forceinline__ float block_reduce_max(float val, float* red) {
    int lane = threadIdx.x & 63, wv = threadIdx.x >> 6;
#pragma unroll
    for (int off = 32; off; off >>= 1) val = fmaxf(val, __shfl_down(val, off, 64));
    if (lane == 0) red[wv] = val;
    __syncthreads();
    float t = fmaxf(fmaxf(red[0], red[1]), fmaxf(red[2], red[3]));
    __syncthreads();
    return t;
}

// ---------------- embedding: h[m][d] = tok_emb[x[m]][d] + pos_emb[m%S][d] ---
__global__ __launch_bounds__(256) void embed_kernel(
    const int* __restrict__ x, const float* __restrict__ tok,
    const float* __restrict__ pos, float* __restrict__ h) {
    int m = blockIdx.x;
    int tid = threadIdx.x;
    int s = m & (SS - 1);
    int t = x[m];
    const float4* trow = (const float4*)(tok + (size_t)t * DD);
    const float4* prow = (const float4*)(pos + (size_t)s * DD);
    float4* hrow = (float4*)(h + (size_t)m * DD);
    float4 a = trow[tid];
    float4 b = prow[tid];
    hrow[tid] = make_float4(a.x + b.x, a.y + b.y, a.z + b.z, a.w + b.w);
}

// ---------------- tiled fp32 GEMM, 128xBN tile, double-buffered LDS ---------
// C[M,N] = A[M,K] @ B + bias[N]  (optional relu)
// BHEAD=0: B is [K,N] row-major.
// BHEAD=1: B is H blocks of [K,64] (wq[l] layout [H,D,DH]); col n maps to
//          head n/64, inner e=n%64. bias is flat [H*64] == [N].
// 256 threads. BN=128: 8x8 per thread. BN=64: 8x4 per thread.
// BM=128 fixed. K multiple of 16, M multiple of 128, N multiple of BN.
template <int BN, int BHEAD, int RELU>
__global__ __launch_bounds__(256, 2) void gemm_kernel(
    const float* __restrict__ A, const float* __restrict__ B,
    const float* __restrict__ bias, float* __restrict__ C,
    int M, int N, int K) {
    constexpr int NQ = BN / 64;  // float4 col-groups per thread (1 or 2)
    __shared__ float sA[2][16][132];      // [k][m], pad keeps 16B align (528B rows)
    __shared__ float sB[2][16][BN + 4];   // [k][n], pad 272B/528B rows

    int tid = threadIdx.x;
    int tx = tid & 15;   // col quad 0..15
    int ty = tid >> 4;   // row quad 0..15
    int n0 = blockIdx.x * BN;
    int m0 = blockIdx.y * 128;

    // A staging: rows ar, ar+64 ; k-cols ac..ac+3
    int ar = tid >> 2;          // 0..63
    int ac = (tid & 3) << 2;    // 0,4,8,12
    // B staging
    int br, bc;
    if (BN == 128) { br = tid >> 5; bc = (tid & 31) << 2; }  // rows br, br+8
    else           { br = tid >> 4; bc = (tid & 15) << 2; }  // row br only

    const float* Ap0 = A + (size_t)(m0 + ar) * K + ac;
    const float* Ap1 = Ap0 + (size_t)64 * K;

    const float* Bp;    // element (k=0, col n0+bc)
    size_t bstride;
    if (BHEAD) {
        Bp = B + (size_t)((n0 + bc) >> 6) * (size_t)K * 64 + ((n0 + bc) & 63);
        bstride = 64;
    } else {
        Bp = B + n0 + bc;
        bstride = (size_t)N;
    }

    float4 a0r, a1r, b0r, b1r = {};

    // prologue: tile 0 → LDS buf 0
    a0r = *(const float4*)(Ap0);
    a1r = *(const float4*)(Ap1);
    b0r = *(const float4*)(Bp + (size_t)br * bstride);
    if (NQ == 2) b1r = *(const float4*)(Bp + (size_t)(br + 8) * bstride);

    sA[0][ac + 0][ar] = a0r.x;
    sA[0][ac + 1][ar] = a0r.y;
    sA[0][ac + 2][ar] = a0r.z;
    sA[0][ac + 3][ar] = a0r.w;
    sA[0][ac + 0][ar + 64] = a1r.x;
    sA[0][ac + 1][ar + 64] = a1r.y;
    sA[0][ac + 2][ar + 64] = a1r.z;
    sA[0][ac + 3][ar + 64] = a1r.w;
    *(float4*)&sB[0][br][bc] = b0r;
    if (NQ == 2) *(float4*)&sB[0][br + 8][bc] = b1r;
    __syncthreads();

    float acc[8][4 * NQ] = {};
    int nk = K >> 4;
    int buf = 0;

    for (int kt = 0; kt < nk; kt++) {
        bool more = (kt + 1) < nk;
        if (more) {
            int k0 = (kt + 1) << 4;
            a0r = *(const float4*)(Ap0 + k0);
            a1r = *(const float4*)(Ap1 + k0);
            b0r = *(const float4*)(Bp + (size_t)(k0 + br) * bstride);
            if (NQ == 2) b1r = *(const float4*)(Bp + (size_t)(k0 + br + 8) * bstride);
        }
#pragma unroll
        for (int kk = 0; kk < 16; kk++) {
            float4 av0 = *(const float4*)&sA[buf][kk][ty * 4];
            float4 av1 = *(const float4*)&sA[buf][kk][ty * 4 + 64];
            float am[8] = {av0.x, av0.y, av0.z, av0.w, av1.x, av1.y, av1.z, av1.w};
            float bn_[8];
            float4 bv0 = *(const float4*)&sB[buf][kk][tx * 4];
            bn_[0] = bv0.x; bn_[1] = bv0.y; bn_[2] = bv0.z; bn_[3] = bv0.w;
            if (NQ == 2) {
                float4 bv1 = *(const float4*)&sB[buf][kk][tx * 4 + 64];
                bn_[4] = bv1.x; bn_[5] = bv1.y; bn_[6] = bv1.z; bn_[7] = bv1.w;
            }
#pragma unroll
            for (int i = 0; i < 8; i++)
#pragma unroll
                for (int j = 0; j < 4 * NQ; j++)
                    acc[i][j] += am[i] * bn_[j];
        }
        if (more) {
            int nb = buf ^ 1;
            sA[nb][ac + 0][ar] = a0r.x;
            sA[nb][ac + 1][ar] = a0r.y;
            sA[nb][ac + 2][ar] = a0r.z;
            sA[nb][ac + 3][ar] = a0r.w;
            sA[nb][ac + 0][ar + 64] = a1r.x;
            sA[nb][ac + 1][ar + 64] = a1r.y;
            sA[nb][ac + 2][ar + 64] = a1r.z;
            sA[nb][ac + 3][ar + 64] = a1r.w;
            *(float4*)&sB[nb][br][bc] = b0r;
            if (NQ == 2) *(float4*)&sB[nb][br + 8][bc] = b1r;
            __syncthreads();
            buf = nb;
        }
    }

    // epilogue
    float4 bia0 = *(const float4*)(bias + n0 + tx * 4);
    float4 bia1 = {};
    if (NQ == 2) bia1 = *(const float4*)(bias + n0 + tx * 4 + 64);
#pragma unroll
    for (int ih = 0; ih < 2; ih++) {
#pragma unroll
        for (int i = 0; i < 4; i++) {
            int ai = ih * 4 + i;
            int mrow = m0 + ih * 64 + ty * 4 + i;
            float* crow = C + (size_t)mrow * N + n0 + tx * 4;
            float4 r;
            r.x = acc[ai][0] + bia0.x;
            r.y = acc[ai][1] + bia0.y;
            r.z = acc[ai][2] + bia0.z;
            r.w = acc[ai][3] + bia0.w;
            if (RELU) {
                r.x = fmaxf(r.x, 0.f); r.y = fmaxf(r.y, 0.f);
                r.z = fmaxf(r.z, 0.f); r.w = fmaxf(r.w, 0.f);
            }
            *(float4*)crow = r;
            if (NQ == 2) {
                float4 r2;
                r2.x = acc[ai][4] + bia1.x;
                r2.y = acc[ai][5] + bia1.y;
                r2.z = acc[ai][6] + bia1.z;
                r2.w = acc[ai][7] + bia1.w;
                if (RELU) {
                    r2.x = fmaxf(r2.x, 0.f); r2.y = fmaxf(r2.y, 0.f);
                    r2.z = fmaxf(r2.z, 0.f); r2.w = fmaxf(r2.w, 0.f);
                }
                *(float4*)(crow + 64) = r2;
            }
        }
    }
}

// ---------------- causal attention, one block per (b,h,s) -------------------
// q,k,v layout: [b, s, h, e] flat = [(b*S+s)*1024 + h*64 + e]
// o layout: [m][d] with d = h*64+e (ready for O-projection GEMM)
__global__ __launch_bounds__(256) void attn_kernel(
    const float* __restrict__ q, const float* __restrict__ k,
    const float* __restrict__ v, float* __restrict__ o) {
    int s = blockIdx.x, hh = blockIdx.y, b = blockIdx.z;
    int tid = threadIdx.x;
    int lane = tid & 63, wv = tid >> 6;

    __shared__ float qs[64];
    __shared__ float sc[SS];
    __shared__ float red[8];
    __shared__ float part[4][64];

    const float scale = 0.125f;  // 1/sqrt(64)
    size_t qoff = ((size_t)(b * SS + s) * HH + hh) * 64;
    if (tid < 64) qs[tid] = q[qoff + tid] * scale;
    __syncthreads();

    int nt = s + 1;
    // phase 1: scores — one key row per wave
    for (int t = wv; t < nt; t += 4) {
        const float* krow = k + ((size_t)(b * SS + t) * HH + hh) * 64;
        float val = qs[lane] * krow[lane];
#pragma unroll
        for (int off = 32; off; off >>= 1) val += __shfl_down(val, off, 64);
        if (lane == 0) sc[t] = val;
    }
    __syncthreads();

    // phase 2: softmax over sc[0..nt)
    float mx = -1e30f;
    for (int t = tid; t < nt; t += 256) mx = fmaxf(mx, sc[t]);
    mx = block_reduce_max(mx, red);
    float sum = 0.f;
    for (int t = tid; t < nt; t += 256) {
        float p = __expf(sc[t] - mx);
        sc[t] = p;
        sum += p;
    }
    sum = block_reduce_sum(sum, red);
    float inv = 1.0f / sum;

    // phase 3: o[e] = inv * sum_t p[t] * v[t][e]
    int e = tid & 63, c = tid >> 6;
    float acc = 0.f;
    for (int t = c; t < nt; t += 4)
        acc += sc[t] * v[((size_t)(b * SS + t) * HH + hh) * 64 + e];
    part[c][e] = acc;
    __syncthreads();
    if (tid < 64) {
        float r = (part[0][tid] + part[1][tid] + part[2][tid] + part[3][tid]) * inv;
        o[(size_t)(b * SS + s) * DD + hh * 64 + tid] = r;
    }
}

// ---------------- LayerNorm(residual): h = LN(tmp + h) * g + b --------------
__global__ __launch_bounds__(256) void ln_res_kernel(
    const float* __restrict__ tmp, float* __restrict__ hbuf,
    const float* __restrict__ g, const float* __restrict__ bta) {
    __shared__ float red[8];
    int m = blockIdx.x, tid = threadIdx.x;
    const float* trow = tmp + (size_t)m * DD;
    float* hrow = hbuf + (size_t)m * DD;
    float v0[4];
    float sum = 0.f;
#pragma unroll
    for (int i = 0; i < 4; i++) {
        int d = tid + 256 * i;
        v0[i] = trow[d] + hrow[d];
        sum += v0[i];
    }
    sum = block_reduce_sum(sum, red);
    float mu = sum * (1.0f / DD);
    float var = 0.f;
#pragma unroll
    for (int i = 0; i < 4; i++) {
        float xv = v0[i] - mu;
        var += xv * xv;
    }
    var = block_reduce_sum(var, red);
    float rstd = rsqrtf(var * (1.0f / DD) + 1e-5f);
#pragma unroll
    for (int i = 0; i < 4; i++) {
        int d = tid + 256 * i;
        hrow[d] = (v0[i] - mu) * rstd * g[d] + bta[d];
    }
}

// ---------------- in-place log_softmax over V=32000 per row -----------------
__global__ __launch_bounds__(256) void logsoftmax_kernel(float* __restrict__ out) {
    __shared__ float red[8];
    int m = blockIdx.x, tid = threadIdx.x;
    float* row = out + (size_t)m * VV;
    float mx = -1e30f;
    for (int t = tid; t < VV; t += 256) mx = fmaxf(mx, row[t]);
    mx = block_reduce_max(mx, red);
    float sum = 0.f;
    for (int t = tid; t < VV; t += 256) sum += __expf(row[t] - mx);
    sum = block_reduce_sum(sum, red);
    float lse = mx + logf(sum);
    for (int t = tid; t < VV; t += 256) row[t] = row[t] - lse;
}

// ---------------- launch ----------------------------------------------------
extern "C" void kernel_launch(void* const* d_in, const int* in_sizes, int n_in,
                              void* d_out, int out_size, void* d_ws, size_t ws_size,
                              hipStream_t stream) {
    const int* x = (const int*)d_in[0];
    const float* tok = (const float*)d_in[1];
    const float* pos = (const float*)d_in[2];
    const float* wq = (const float*)d_in[3];
    const float* bq = (const float*)d_in[4];
    const float* wk = (const float*)d_in[5];
    const float* bk = (const float*)d_in[6];
    const float* wv = (const float*)d_in[7];
    const float* bv = (const float*)d_in[8];
    const float* wo = (const float*)d_in[9];
    const float* bo = (const float*)d_in[10];
    const float* ln1g = (const float*)d_in[11];
    const float* ln1b = (const float*)d_in[12];
    const float* w1 = (const float*)d_in[13];
    const float* b1 = (const float*)d_in[14];
    const float* w2 = (const float*)d_in[15];
    const float* b2 = (const float*)d_in[16];
    const float* ln2g = (const float*)d_in[17];
    const float* ln2b = (const float*)d_in[18];
    const float* wout = (const float*)d_in[19];
    const float* bout = (const float*)d_in[20];
    float* out = (float*)d_out;
    float* ws = (float*)d_ws;

    // workspace layout (floats):
    // h: 2M | big: 8M (q,k,v share first 6M; ff uses all 8M) | o: 2M | t1: 2M
    const size_t SZ = (size_t)MM * DD;  // 2M floats
    float* h = ws;
    float* big = ws + SZ;
    float* qb = big;
    float* kb = big + SZ;
    float* vb = big + 2 * SZ;
    float* ffb = big;  // reuses q/k/v space (8M floats)
    float* ob = ws + 5 * SZ;
    float* t1 = ws + 6 * SZ;

    const size_t wqk_l = (size_t)HH * DD * DHH;  // 1,048,576
    const size_t wo_l = (size_t)DD * DD;
    const size_t w1_l = (size_t)DD * FFDIM;
    const size_t w2_l = (size_t)FFDIM * DD;

    dim3 blk(256);

    embed_kernel<<<MM, blk, 0, stream>>>(x, tok, pos, h);

    for (int l = 0; l < LL; l++) {
        // QKV projections (head-batched weight layout [H,D,DH]) — BN=64 → 256 blocks
        gemm_kernel<64, 1, 0><<<dim3(DD / 64, MM / 128), blk, 0, stream>>>(
            h, wq + l * wqk_l, bq + (size_t)l * DD, qb, MM, DD, DD);
        gemm_kernel<64, 1, 0><<<dim3(DD / 64, MM / 128), blk, 0, stream>>>(
            h, wk + l * wqk_l, bk + (size_t)l * DD, kb, MM, DD, DD);
        gemm_kernel<64, 1, 0><<<dim3(DD / 64, MM / 128), blk, 0, stream>>>(
            h, wv + l * wqk_l, bv + (size_t)l * DD, vb, MM, DD, DD);

        attn_kernel<<<dim3(SS, HH, BB), blk, 0, stream>>>(qb, kb, vb, ob);

        // O-projection — BN=64 → 256 blocks
        gemm_kernel<64, 0, 0><<<dim3(DD / 64, MM / 128), blk, 0, stream>>>(
            ob, wo + l * wo_l, bo + (size_t)l * DD, t1, MM, DD, DD);
        ln_res_kernel<<<MM, blk, 0, stream>>>(t1, h, ln1g + (size_t)l * DD,
                                              ln1b + (size_t)l * DD);

        // FF1 (N=4096) — BN=128 → 512 blocks
        gemm_kernel<128, 0, 1><<<dim3(FFDIM / 128, MM / 128), blk, 0, stream>>>(
            h, w1 + l * w1_l, b1 + (size_t)l * FFDIM, ffb, MM, FFDIM, DD);
        // FF2 (N=1024, K=4096) — BN=64 → 256 blocks
        gemm_kernel<64, 0, 0><<<dim3(DD / 64, MM / 128), blk, 0, stream>>>(
            ffb, w2 + l * w2_l, b2 + (size_t)l * DD, t1, MM, DD, FFDIM);
        ln_res_kernel<<<MM, blk, 0, stream>>>(t1, h, ln2g + (size_t)l * DD,
                                              ln2b + (size_t)l * DD);
    }

    // logits straight into d_out, then in-place log_softmax — BN=128 → 4000 blocks
    gemm_kernel<128, 0, 0><<<dim3(VV / 128, MM / 128), blk, 0, stream>>>(
        h, wout, bout, out, MM, VV, DD);
    logsoftmax_kernel<<<MM, blk, 0, stream>>>(out);
}